// Round 1
// baseline (255.153 us; speedup 1.0000x reference)
//
#include <hip/hip_runtime.h>

#define NFP   10000
#define DIM   70
#define DPAD  72
#define NATOMS 64

typedef short  short8  __attribute__((ext_vector_type(8)));
typedef float  floatx4 __attribute__((ext_vector_type(4)));

__device__ inline unsigned short f2bf(float f) {
  union { float f; unsigned u; } x; x.f = f;
  unsigned r = x.u + 0x7fffu + ((x.u >> 16) & 1u);   // round-to-nearest-even
  return (unsigned short)(r >> 16);
}

// G[v][72] (bf16, cols 70,71 = 0) = relu(emb[v] @ w1 + b1) @ w2
// 32 vocab rows per block.
__global__ __launch_bounds__(256) void precompute_G(
    const float* __restrict__ emb, const float* __restrict__ w1,
    const float* __restrict__ b1,  const float* __restrict__ w2,
    unsigned short* __restrict__ G) {
  __shared__ float w1s[DIM * DPAD];
  __shared__ float w2s[DIM * DPAD];
  __shared__ float b1s[DPAD];
  __shared__ float embs[32 * DPAD];
  __shared__ float e1s[32 * DPAD];
  const int t = threadIdx.x;

  for (int i = t; i < DIM * DPAD; i += 256) {
    int r = i / DPAD, c = i % DPAD;
    float v1 = 0.f, v2 = 0.f;
    if (c < DIM) { v1 = w1[r * DIM + c]; v2 = w2[r * DIM + c]; }
    w1s[i] = v1; w2s[i] = v2;
  }
  if (t < DPAD) b1s[t] = (t < DIM) ? b1[t] : 0.f;
  const int row0 = blockIdx.x * 32;
  for (int i = t; i < 32 * DPAD; i += 256) {
    int r = i / DPAD, c = i % DPAD;
    int vr = row0 + r;
    embs[i] = (vr < NFP && c < DIM) ? emb[vr * DIM + c] : 0.f;
  }
  __syncthreads();

  // E1 = relu(emb @ w1 + b1)
  for (int task = t; task < 32 * 18; task += 256) {
    int r = task / 18, c4 = (task % 18) * 4;
    float4 acc = *(const float4*)&b1s[c4];
    for (int k = 0; k < DIM; k++) {
      float e = embs[r * DPAD + k];
      float4 w = *(const float4*)&w1s[k * DPAD + c4];
      acc.x = fmaf(e, w.x, acc.x); acc.y = fmaf(e, w.y, acc.y);
      acc.z = fmaf(e, w.z, acc.z); acc.w = fmaf(e, w.w, acc.w);
    }
    acc.x = fmaxf(acc.x, 0.f); acc.y = fmaxf(acc.y, 0.f);
    acc.z = fmaxf(acc.z, 0.f); acc.w = fmaxf(acc.w, 0.f);
    *(float4*)&e1s[r * DPAD + c4] = acc;
  }
  __syncthreads();

  // G = E1 @ w2  (store bf16)
  for (int task = t; task < 32 * 18; task += 256) {
    int r = task / 18, c4 = (task % 18) * 4;
    int vr = row0 + r;
    if (vr >= NFP) continue;
    float ax = 0.f, ay = 0.f, az = 0.f, aw = 0.f;
    for (int k = 0; k < DIM; k++) {
      float e = e1s[r * DPAD + k];
      float4 w = *(const float4*)&w2s[k * DPAD + c4];
      ax = fmaf(e, w.x, ax); ay = fmaf(e, w.y, ay);
      az = fmaf(e, w.z, az); aw = fmaf(e, w.w, aw);
    }
    unsigned short* gp = G + vr * DPAD + c4;
    gp[0] = f2bf(ax); gp[1] = f2bf(ay); gp[2] = f2bf(az); gp[3] = f2bf(aw);
  }
}

// One block per molecule: h2 = relu(adj @ G[atoms] + b2); out = [colsum(adj)@h2, sel] @ wp + bp
__global__ __launch_bounds__(256) void mol_fused(
    const int* __restrict__ atoms, const float* __restrict__ adj,
    const float* __restrict__ sel, const float* __restrict__ b2,
    const float* __restrict__ wp,  const float* __restrict__ bp,
    const unsigned short* __restrict__ G, float* __restrict__ out) {
  __shared__ unsigned short adjs[64 * DPAD];   // adj row-major, bf16, pad 72
  __shared__ unsigned short gTs[80 * DPAD];    // g transposed: gT[d][m], bf16
  __shared__ float cpart[16 * 64];
  __shared__ float cvec[64];
  __shared__ float b2p[80];
  __shared__ float yacc[16 * 80];
  __shared__ float yv[80];
  __shared__ int   satoms[64];

  const int b = blockIdx.x;
  const int t = threadIdx.x;

  if (t < 64) satoms[t] = atoms[b * 64 + t];
  if (t < 80) b2p[t] = (t < DIM) ? b2[t] : 0.f;
  __syncthreads();

  // Stage adjacency fp32 -> bf16 LDS; fp32 column partial sums on the fly.
  {
    const float* ap = adj + (size_t)b * 4096;
    const int mc = (t & 15) * 4;   // column base
    const int a  = t >> 4;         // row-group
    float4 cs = make_float4(0.f, 0.f, 0.f, 0.f);
#pragma unroll
    for (int it = 0; it < 4; it++) {
      int n = a + 16 * it;
      float4 v = *(const float4*)(ap + n * 64 + mc);
      cs.x += v.x; cs.y += v.y; cs.z += v.z; cs.w += v.w;
      ushort4 u;
      u.x = f2bf(v.x); u.y = f2bf(v.y); u.z = f2bf(v.z); u.w = f2bf(v.w);
      *(ushort4*)&adjs[n * DPAD + mc] = u;
    }
    *(float4*)&cpart[a * 64 + mc] = cs;
  }

  // Gather G[atoms] rows (uint4 = 8 bf16) and transpose into gT[d][m].
  {
    const int m = t & 63;
    const int row = satoms[m];
    const uint4* Gv = (const uint4*)G;   // 72 bf16 = 9 uint4 per row
    for (int ch = (t >> 6); ch < 9; ch += 4) {
      uint4 v = Gv[row * 9 + ch];
      unsigned short* gp = &gTs[(ch * 8) * DPAD + m];
      gp[0 * DPAD] = (unsigned short)(v.x & 0xffff);
      gp[1 * DPAD] = (unsigned short)(v.x >> 16);
      gp[2 * DPAD] = (unsigned short)(v.y & 0xffff);
      gp[3 * DPAD] = (unsigned short)(v.y >> 16);
      gp[4 * DPAD] = (unsigned short)(v.z & 0xffff);
      gp[5 * DPAD] = (unsigned short)(v.z >> 16);
      gp[6 * DPAD] = (unsigned short)(v.w & 0xffff);
      gp[7 * DPAD] = (unsigned short)(v.w >> 16);
    }
    for (int i = t; i < 8 * DPAD; i += 256) gTs[72 * DPAD + i] = 0;  // pad rows 72..79
  }
  __syncthreads();

  // Combine adjacency column sums (exact fp32).
  if (t < 64) {
    float s = 0.f;
#pragma unroll
    for (int a = 0; a < 16; a++) s += cpart[a * 64 + t];
    cvec[t] = s;
  }

  // MFMA: x1h[64][80] = adj @ g.  Wave w owns rows 16w..16w+15.
  const int w = t >> 6, lane = t & 63;
  const int q = lane >> 4, li = lane & 15;
  const int R = w * 16;
  short8 a0 = *(const short8*)&adjs[(R + li) * DPAD + q * 8];
  short8 a1 = *(const short8*)&adjs[(R + li) * DPAD + 32 + q * 8];
  floatx4 acc[5];
#pragma unroll
  for (int nt = 0; nt < 5; nt++) {
    floatx4 z = {0.f, 0.f, 0.f, 0.f};
    short8 b0 = *(const short8*)&gTs[(nt * 16 + li) * DPAD + q * 8];
    short8 b1 = *(const short8*)&gTs[(nt * 16 + li) * DPAD + 32 + q * 8];
    z = __builtin_amdgcn_mfma_f32_16x16x32_bf16(a0, b0, z, 0, 0, 0);
    z = __builtin_amdgcn_mfma_f32_16x16x32_bf16(a1, b1, z, 0, 0, 0);
    acc[nt] = z;
  }
  __syncthreads();   // cvec visible; all frag reads done

  // Epilogue: h2 = relu(x1h + b2); per-lane partial of y[d] = sum_m cvec[m]*h2[m][d]
#pragma unroll
  for (int nt = 0; nt < 5; nt++) {
    int d = nt * 16 + li;
    float bb = b2p[d];
    float ps = 0.f;
#pragma unroll
    for (int r = 0; r < 4; r++) {
      float h = fmaxf(acc[nt][r] + bb, 0.f);
      ps = fmaf(cvec[R + q * 4 + r], h, ps);
    }
    yacc[(w * 4 + q) * 80 + d] = ps;
  }
  __syncthreads();

  if (t < 80) {
    float s = 0.f;
#pragma unroll
    for (int i = 0; i < 16; i++) s += yacc[i * 80 + t];
    yv[t] = (t < DIM) ? s : ((t < DIM + 7) ? sel[b * 7 + (t - DIM)] : 0.f);
  }
  __syncthreads();

  if (t < 11) {
    float s = bp[t];
    for (int d = 0; d < 77; d++) s = fmaf(yv[d], wp[d * 11 + t], s);
    out[b * 11 + t] = s;
  }
}

extern "C" void kernel_launch(void* const* d_in, const int* in_sizes, int n_in,
                              void* d_out, int out_size, void* d_ws, size_t ws_size,
                              hipStream_t stream) {
  const int*   atoms = (const int*)d_in[0];
  const float* adj   = (const float*)d_in[1];
  const float* sel   = (const float*)d_in[2];
  const float* emb   = (const float*)d_in[3];
  const float* w1    = (const float*)d_in[4];
  const float* b1    = (const float*)d_in[5];
  const float* w2    = (const float*)d_in[6];
  const float* b2    = (const float*)d_in[7];
  const float* wp    = (const float*)d_in[8];
  const float* bp    = (const float*)d_in[9];

  const int B = in_sizes[0] / NATOMS;          // 8192
  unsigned short* G = (unsigned short*)d_ws;   // 10000*72 bf16 = 1.44 MB

  precompute_G<<<(NFP + 31) / 32, 256, 0, stream>>>(emb, w1, b1, w2, G);
  mol_fused<<<B, 256, 0, stream>>>(atoms, adj, sel, b2, wp, bp, G, (float*)d_out);
}

// Round 2
// 255.056 us; speedup vs baseline: 1.0004x; 1.0004x over previous
//
#include <hip/hip_runtime.h>
#include <hip/hip_bf16.h>

#define NFP   10000
#define DIM   70
#define DPAD  72
#define NATOMS 64

typedef short  short8  __attribute__((ext_vector_type(8)));
typedef float  floatx4 __attribute__((ext_vector_type(4)));

__device__ inline unsigned short f2bf(float f) {
  union { float f; unsigned u; } x; x.f = f;
  unsigned r = x.u + 0x7fffu + ((x.u >> 16) & 1u);   // round-to-nearest-even
  return (unsigned short)(r >> 16);
}

__device__ inline ushort2 pk2bf(float a, float b) {
  __hip_bfloat162 h = __float22bfloat162_rn(make_float2(a, b));
  union { __hip_bfloat162 h; ushort2 u; } c; c.h = h; return c.u;
}

// G[v][72] (bf16, cols 70,71 = 0) = relu(emb[v] @ w1 + b1) @ w2
__global__ __launch_bounds__(256) void precompute_G(
    const float* __restrict__ emb, const float* __restrict__ w1,
    const float* __restrict__ b1,  const float* __restrict__ w2,
    unsigned short* __restrict__ G) {
  __shared__ float w1s[DIM * DPAD];
  __shared__ float w2s[DIM * DPAD];
  __shared__ float b1s[DPAD];
  __shared__ float embs[32 * DPAD];
  __shared__ float e1s[32 * DPAD];
  const int t = threadIdx.x;

  for (int i = t; i < DIM * DPAD; i += 256) {
    int r = i / DPAD, c = i % DPAD;
    float v1 = 0.f, v2 = 0.f;
    if (c < DIM) { v1 = w1[r * DIM + c]; v2 = w2[r * DIM + c]; }
    w1s[i] = v1; w2s[i] = v2;
  }
  if (t < DPAD) b1s[t] = (t < DIM) ? b1[t] : 0.f;
  const int row0 = blockIdx.x * 32;
  for (int i = t; i < 32 * DPAD; i += 256) {
    int r = i / DPAD, c = i % DPAD;
    int vr = row0 + r;
    embs[i] = (vr < NFP && c < DIM) ? emb[vr * DIM + c] : 0.f;
  }
  __syncthreads();

  for (int task = t; task < 32 * 18; task += 256) {
    int r = task / 18, c4 = (task % 18) * 4;
    float4 acc = *(const float4*)&b1s[c4];
    for (int k = 0; k < DIM; k++) {
      float e = embs[r * DPAD + k];
      float4 w = *(const float4*)&w1s[k * DPAD + c4];
      acc.x = fmaf(e, w.x, acc.x); acc.y = fmaf(e, w.y, acc.y);
      acc.z = fmaf(e, w.z, acc.z); acc.w = fmaf(e, w.w, acc.w);
    }
    acc.x = fmaxf(acc.x, 0.f); acc.y = fmaxf(acc.y, 0.f);
    acc.z = fmaxf(acc.z, 0.f); acc.w = fmaxf(acc.w, 0.f);
    *(float4*)&e1s[r * DPAD + c4] = acc;
  }
  __syncthreads();

  for (int task = t; task < 32 * 18; task += 256) {
    int r = task / 18, c4 = (task % 18) * 4;
    int vr = row0 + r;
    if (vr >= NFP) continue;
    float ax = 0.f, ay = 0.f, az = 0.f, aw = 0.f;
    for (int k = 0; k < DIM; k++) {
      float e = e1s[r * DPAD + k];
      float4 w = *(const float4*)&w2s[k * DPAD + c4];
      ax = fmaf(e, w.x, ax); ay = fmaf(e, w.y, ay);
      az = fmaf(e, w.z, az); aw = fmaf(e, w.w, aw);
    }
    unsigned short* gp = G + vr * DPAD + c4;
    gp[0] = f2bf(ax); gp[1] = f2bf(ay); gp[2] = f2bf(az); gp[3] = f2bf(aw);
  }
}

// One block per molecule: h2 = relu(adj @ G[atoms] + b2); y = colsum(adj) @ h2 -> ws
__global__ __launch_bounds__(256) void mol_fused(
    const int* __restrict__ atoms, const float* __restrict__ adj,
    const float* __restrict__ b2,  const unsigned short* __restrict__ G,
    float* __restrict__ yws) {
  __shared__ unsigned short adjs[64 * DPAD];   // adj row-major, bf16, pad 72
  __shared__ unsigned short gTs[80 * DPAD];    // g transposed: gT[d][m], bf16
  __shared__ float cwave[4 * 64];
  __shared__ float cvec[64];
  __shared__ float b2p[80];
  __shared__ float yacc[4 * 80];
  __shared__ int   satoms[64];

  const int b = blockIdx.x;
  const int t = threadIdx.x;
  const int w = t >> 6, lane = t & 63;
  const int q = lane >> 4, li = lane & 15;

  if (t < 64) satoms[t] = atoms[b * 64 + t];
  if (t < 80) b2p[t] = (t < DIM) ? b2[t] : 0.f;
  __syncthreads();

  // Stage adjacency fp32 -> bf16 LDS (packed cvt); colsum partials via shuffle.
  {
    const float* ap = adj + (size_t)b * 4096;
    const int mc = (t & 15) * 4;   // column base
    const int a  = t >> 4;         // row-group
    float4 cs = make_float4(0.f, 0.f, 0.f, 0.f);
#pragma unroll
    for (int it = 0; it < 4; it++) {
      int n = a + 16 * it;
      float4 v = *(const float4*)(ap + n * 64 + mc);
      cs.x += v.x; cs.y += v.y; cs.z += v.z; cs.w += v.w;
      ushort2 lo = pk2bf(v.x, v.y);
      ushort2 hi = pk2bf(v.z, v.w);
      ushort4 u; u.x = lo.x; u.y = lo.y; u.z = hi.x; u.w = hi.y;
      *(ushort4*)&adjs[n * DPAD + mc] = u;
    }
    // reduce over the 4 row-groups within this wave (t bits 4..5)
#pragma unroll
    for (int s = 16; s <= 32; s <<= 1) {
      cs.x += __shfl_xor(cs.x, s); cs.y += __shfl_xor(cs.y, s);
      cs.z += __shfl_xor(cs.z, s); cs.w += __shfl_xor(cs.w, s);
    }
    if (((t >> 4) & 3) == 0) *(float4*)&cwave[w * 64 + mc] = cs;
  }

  // Gather G[atoms] rows (uint4 = 8 bf16) and transpose into gT[d][m].
  {
    const int m = t & 63;
    const int row = satoms[m];
    const uint4* Gv = (const uint4*)G;   // 72 bf16 = 9 uint4 per row
    for (int ch = w; ch < 9; ch += 4) {
      uint4 v = Gv[row * 9 + ch];
      unsigned short* gp = &gTs[(ch * 8) * DPAD + m];
      gp[0 * DPAD] = (unsigned short)(v.x & 0xffff);
      gp[1 * DPAD] = (unsigned short)(v.x >> 16);
      gp[2 * DPAD] = (unsigned short)(v.y & 0xffff);
      gp[3 * DPAD] = (unsigned short)(v.y >> 16);
      gp[4 * DPAD] = (unsigned short)(v.z & 0xffff);
      gp[5 * DPAD] = (unsigned short)(v.z >> 16);
      gp[6 * DPAD] = (unsigned short)(v.w & 0xffff);
      gp[7 * DPAD] = (unsigned short)(v.w >> 16);
    }
    for (int i = t; i < 8 * DPAD; i += 256) gTs[72 * DPAD + i] = 0;  // rows 72..79
  }
  __syncthreads();

  // Combine adjacency column sums (exact fp32).
  if (t < 64) {
    cvec[t] = cwave[t] + cwave[64 + t] + cwave[128 + t] + cwave[192 + t];
  }

  // MFMA: x1h[64][80] = adj @ g.  Wave w owns rows 16w..16w+15.
  const int R = w * 16;
  short8 a0 = *(const short8*)&adjs[(R + li) * DPAD + q * 8];
  short8 a1 = *(const short8*)&adjs[(R + li) * DPAD + 32 + q * 8];
  floatx4 acc[5];
#pragma unroll
  for (int nt = 0; nt < 5; nt++) {
    floatx4 z = {0.f, 0.f, 0.f, 0.f};
    short8 b0 = *(const short8*)&gTs[(nt * 16 + li) * DPAD + q * 8];
    short8 b1 = *(const short8*)&gTs[(nt * 16 + li) * DPAD + 32 + q * 8];
    z = __builtin_amdgcn_mfma_f32_16x16x32_bf16(a0, b0, z, 0, 0, 0);
    z = __builtin_amdgcn_mfma_f32_16x16x32_bf16(a1, b1, z, 0, 0, 0);
    acc[nt] = z;
  }
  __syncthreads();   // cvec visible; all frag reads done

  // Epilogue: h2 = relu(x1h + b2); y[d] = sum_m cvec[m]*h2[m][d]
  float ps[5];
#pragma unroll
  for (int nt = 0; nt < 5; nt++) {
    int d = nt * 16 + li;
    float bb = b2p[d];
    float p = 0.f;
#pragma unroll
    for (int r = 0; r < 4; r++) {
      float h = fmaxf(acc[nt][r] + bb, 0.f);
      p = fmaf(cvec[R + q * 4 + r], h, p);
    }
    p += __shfl_xor(p, 16);   // reduce over q (rows within wave)
    p += __shfl_xor(p, 32);
    ps[nt] = p;
  }
  if (q == 0) {
#pragma unroll
    for (int nt = 0; nt < 5; nt++) yacc[w * 80 + nt * 16 + li] = ps[nt];
  }
  __syncthreads();

  if (t < DIM) {
    float s = yacc[t] + yacc[80 + t] + yacc[160 + t] + yacc[240 + t];
    yws[(size_t)b * DIM + t] = s;
  }
}

// out[b][c] = [y[b], sel[b]] @ wp + bp  -- fully parallel
__global__ __launch_bounds__(256) void proj_out(
    const float* __restrict__ yws, const float* __restrict__ sel,
    const float* __restrict__ wp,  const float* __restrict__ bp,
    float* __restrict__ out, int B) {
  __shared__ float wps[77 * 11];
  __shared__ float bps[11];
  const int t = threadIdx.x;
  for (int i = t; i < 77 * 11; i += 256) wps[i] = wp[i];
  if (t < 11) bps[t] = bp[t];
  __syncthreads();
  const int gid = blockIdx.x * 256 + t;
  if (gid >= B * 11) return;
  const int b = gid / 11, c = gid % 11;
  float s = bps[c];
  const float* yp = yws + (size_t)b * DIM;
#pragma unroll 7
  for (int d = 0; d < DIM; d++) s = fmaf(yp[d], wps[d * 11 + c], s);
  const float* sp = sel + (size_t)b * 7;
#pragma unroll
  for (int d = 0; d < 7; d++) s = fmaf(sp[d], wps[(DIM + d) * 11 + c], s);
  out[gid] = s;
}

extern "C" void kernel_launch(void* const* d_in, const int* in_sizes, int n_in,
                              void* d_out, int out_size, void* d_ws, size_t ws_size,
                              hipStream_t stream) {
  const int*   atoms = (const int*)d_in[0];
  const float* adj   = (const float*)d_in[1];
  const float* sel   = (const float*)d_in[2];
  const float* emb   = (const float*)d_in[3];
  const float* w1    = (const float*)d_in[4];
  const float* b1    = (const float*)d_in[5];
  const float* w2    = (const float*)d_in[6];
  const float* b2    = (const float*)d_in[7];
  const float* wp    = (const float*)d_in[8];
  const float* bp    = (const float*)d_in[9];

  const int B = in_sizes[0] / NATOMS;          // 8192
  unsigned short* G = (unsigned short*)d_ws;   // 10000*72 bf16 = 1.44 MB
  float* yws = (float*)((char*)d_ws + (2 << 20));  // y[B][70] fp32 = 2.3 MB

  precompute_G<<<(NFP + 31) / 32, 256, 0, stream>>>(emb, w1, b1, w2, G);
  mol_fused<<<B, 256, 0, stream>>>(atoms, adj, b2, G, yws);
  proj_out<<<(B * 11 + 255) / 256, 256, 0, stream>>>(yws, sel, wp, bp, (float*)d_out, B);
}